// Round 8
// baseline (327.109 us; speedup 1.0000x reference)
//
#include <hip/hip_runtime.h>

#define BATCH 4
#define SEQ   2048
#define EMB   128
#define NH    16
#define DK    8

// log2(e) / sqrt(8): fold softmax temperature into exp2 (pre-multiplied into qf)
#define QSCALE 0.510069726f

typedef _Float16 v4h  __attribute__((ext_vector_type(4)));
typedef _Float16 v8h  __attribute__((ext_vector_type(8)));
typedef __fp16   v2fp __attribute__((ext_vector_type(2)));
typedef float    v4f  __attribute__((ext_vector_type(4)));
typedef float    v16f __attribute__((ext_vector_type(16)));

// ---------------------------------------------------------------------------
// R23: unconfounded occupancy doubling. R20's wall is ~346 cyc per
// chain-iter-slot vs ~90-150 cyc of issue => latency-bound at 4 waves/SIMD,
// NOT issue-saturated. R16's "occupancy doesn't help" was confounded
// (launch_bounds squeezed VGPR 44->32, wrecking the pipeline); the R20
// kernel needs only 52 VGPR and fits the 64-cap of 8 waves/SIMD unsqueezed.
// Change: blocks go 256->512 threads (8 waves): wave wv takes key-quarter
// (wv&3, 16 K-tiles) and q-pair (wv>>2). Grid stays 1024 => 4 blocks/CU x
// 8 waves = 32 waves/CU = 8/SIMD (was 4). LDS combine is now a 4-way sum
// (P[8][2][5][64] = 20 KB; 80 KB/CU). Inner loop, per-block F traffic,
// and total chain-iters are IDENTICAL to R20.
//
// attn structure (R20, HW-verified): each wave runs TWO q-chains sharing
// kf/vt/addr/loop; plain-exp partials additive, combined in LDS.
// S^T = mfma_32x32x16(A=K, B=Q^T); C/D col=L&31, row=(reg&3)+8(reg>>2)+
// 4(L>>5). P=exp2(S^T) packs with pkrtz in natural order into the PV B-frag
// given the F2-baked key perm (bits 2<->3). qf=0 on half1 kills k=8..15
// padding. Ones-row 8 of F2 = denominator. |score*log2e/sqrt8| <= 4.1.
// ---------------------------------------------------------------------------

__launch_bounds__(256, 4)
__global__ void feat_kernel(const float* __restrict__ x,
                            const float* __restrict__ theta,
                            _Float16* __restrict__ F1,
                            _Float16* __restrict__ F2) {
  const int tid = threadIdx.x;
  const int bh  = blockIdx.x >> 3;          // 64 (b,h)
  const int s   = ((blockIdx.x & 7) << 8) + tid;
  const int b = bh >> 4, h = bh & 15;

  float th[8];
#pragma unroll
  for (int i = 0; i < 8; ++i) th[i] = theta[i];

  const float* xp = x + ((size_t)b * SEQ + s) * EMB + h * DK;
  const float4 a = *(const float4*)(xp);
  const float4 c = *(const float4*)(xp + 4);
  float r[8];
  r[0] = __cosf(a.x + th[0]);
  r[1] = r[0] * __cosf(a.y + th[1]);
  r[2] = r[1] * __cosf(a.z + th[2]);
  r[3] = r[2] * __cosf(a.w + th[3]);
  r[4] = r[3] * __cosf(c.x + th[4]);
  r[5] = r[4] * __cosf(c.y + th[5]);
  r[6] = r[5] * __cosf(c.z + th[6]);
  r[7] = r[6] * __cosf(c.w + th[7]);

  _Float16 hv[8];
#pragma unroll
  for (int i = 0; i < 8; ++i) hv[i] = (_Float16)r[i];

  // F1[bh][s][8]: 16 B contiguous store, s-consecutive lanes => coalesced
  union { v4h v[2]; float4 f; } u;
  u.v[0] = (v4h){hv[0], hv[1], hv[2], hv[3]};
  u.v[1] = (v4h){hv[4], hv[5], hv[6], hv[7]};
  *(float4*)(F1 + ((size_t)bh * SEQ + s) * 8) = u.f;

  // F2[bh][d][s_perm]: key-index bits 2<->3 swap baked in; per-d stores are
  // s-coalesced (permutation stays within each 16-group / 32 B)
  const int sp = (s & ~15) | (s & 3) | ((s & 4) << 1) | ((s & 8) >> 1);
  _Float16* f2 = F2 + (size_t)bh * 9 * SEQ;
#pragma unroll
  for (int d = 0; d < 8; ++d) f2[(size_t)d * SEQ + sp] = hv[d];
  f2[(size_t)8 * SEQ + s] = (_Float16)1.0f;   // denominator ones-row
}

__launch_bounds__(512, 8)
__global__ void attn_kernel(const _Float16* __restrict__ F1,
                            const _Float16* __restrict__ F2,
                            _Float16* __restrict__ Ah /* [B*S][128] f16 */) {
  __shared__ float P[8][2][5][64];          // 20 KB partial-combine buffer

  const int tid = threadIdx.x;
  const int L   = tid & 63;
  const int ln  = L & 31;
  const int hf  = L >> 5;                   // lane half
  const int wv  = tid >> 6;                 // wave 0..7
  const int kh  = wv & 3;                   // key quarter
  const int pr  = wv >> 2;                  // q-pair 0..1
  const int bh  = blockIdx.x >> 4;
  const int qbase = (blockIdx.x & 15) * 128;
  const int b = bh >> 4, h = bh & 15;
  const int mrow = (ln < 8) ? ln : 8;       // V^T row; ln>=8 -> ones-row 8

  const _Float16* f1 = F1 + (size_t)bh * SEQ * 8;
  const _Float16* kp = f1 + (size_t)(kh * 512 + ln) * 8;    // this quarter's K
  const _Float16* vp = F2 + (size_t)bh * 9 * SEQ + (size_t)mrow * SEQ
                          + kh * 512 + hf * 8;

  // two q-fragments (q-tiles 2*pr and 2*pr+1); half1 stays 0
  v8h qf0 = {0, 0, 0, 0, 0, 0, 0, 0};
  v8h qf1 = {0, 0, 0, 0, 0, 0, 0, 0};
  if (hf == 0) {
    const _Float16 qs = (_Float16)QSCALE;
    const v8h qsc = {qs, qs, qs, qs, qs, qs, qs, qs};
    qf0 = *(const v8h*)(f1 + (size_t)(qbase + pr * 64 + ln) * 8) * qsc;
    qf1 = *(const v8h*)(f1 + (size_t)(qbase + pr * 64 + 32 + ln) * 8) * qsc;
  }

  v16f acc0, acc1, zf;
#pragma unroll
  for (int i = 0; i < 16; ++i) { acc0[i] = 0.f; acc1[i] = 0.f; zf[i] = 0.f; }

  // ---- 16 K-tiles, dual chain, kf 1-deep prefetch ----
  v8h kf = *(const v8h*)kp; kp += 256;
#pragma unroll 4
  for (int kb = 0; kb < 16; ++kb) {
    const v8h kf_n = *(const v8h*)kp; kp += 256;   // next tile (pad-safe at end)
    const v16f s0 = __builtin_amdgcn_mfma_f32_32x32x16_f16(kf, qf0, zf, 0, 0, 0);
    const v16f s1 = __builtin_amdgcn_mfma_f32_32x32x16_f16(kf, qf1, zf, 0, 0, 0);
    const v8h vt0 = *(const v8h*)(vp);
    const v8h vt1 = *(const v8h*)(vp + 16); vp += 32;
    union { v2fp p[4]; v8h v; } a0, a1, b0, b1;
#pragma unroll
    for (int i = 0; i < 4; ++i) {
      a0.p[i] = __builtin_amdgcn_cvt_pkrtz(
          __builtin_amdgcn_exp2f(s0[2 * i]),
          __builtin_amdgcn_exp2f(s0[2 * i + 1]));
      a1.p[i] = __builtin_amdgcn_cvt_pkrtz(
          __builtin_amdgcn_exp2f(s0[8 + 2 * i]),
          __builtin_amdgcn_exp2f(s0[8 + 2 * i + 1]));
    }
    acc0 = __builtin_amdgcn_mfma_f32_32x32x16_f16(vt0, a0.v, acc0, 0, 0, 0);
    acc0 = __builtin_amdgcn_mfma_f32_32x32x16_f16(vt1, a1.v, acc0, 0, 0, 0);
#pragma unroll
    for (int i = 0; i < 4; ++i) {
      b0.p[i] = __builtin_amdgcn_cvt_pkrtz(
          __builtin_amdgcn_exp2f(s1[2 * i]),
          __builtin_amdgcn_exp2f(s1[2 * i + 1]));
      b1.p[i] = __builtin_amdgcn_cvt_pkrtz(
          __builtin_amdgcn_exp2f(s1[8 + 2 * i]),
          __builtin_amdgcn_exp2f(s1[8 + 2 * i + 1]));
    }
    acc1 = __builtin_amdgcn_mfma_f32_32x32x16_f16(vt0, b0.v, acc1, 0, 0, 0);
    acc1 = __builtin_amdgcn_mfma_f32_32x32x16_f16(vt1, b1.v, acc1, 0, 0, 0);
    kf = kf_n;
  }

  // ---- epilogue: 4-way combine of key-quarter partials ----
  // acc C-layout: col=q=L&31, row=(reg&3)+8(reg>>2)+4*hf.
  // half0 regs 0-3 = dims 0-3, reg4 = row 8 = den; half1 regs 0-3 = dims 4-7.
#pragma unroll
  for (int r = 0; r < 5; ++r) {
    P[wv][0][r][L] = acc0[r];
    P[wv][1][r][L] = acc1[r];
  }
  __syncthreads();
  if (kh < 2) {
    const int c  = kh;                  // chain handled by this wave
    const int g  = pr * 4;              // base wave of this q-pair's group
    float sum[4];
#pragma unroll
    for (int r = 0; r < 4; ++r)
      sum[r] = (P[g][c][r][L] + P[g + 1][c][r][L]) +
               (P[g + 2][c][r][L] + P[g + 3][c][r][L]);
    const float den = (P[g][c][4][ln] + P[g + 1][c][4][ln]) +
                      (P[g + 2][c][4][ln] + P[g + 3][c][4][ln]);
    const float inv = 1.0f / den;
    const int qrow = qbase + (pr * 2 + c) * 32 + ln;
    v4h o = {(_Float16)(sum[0] * inv), (_Float16)(sum[1] * inv),
             (_Float16)(sum[2] * inv), (_Float16)(sum[3] * inv)};
    *(v4h*)(Ah + ((size_t)b * SEQ + qrow) * EMB + h * DK + hf * 4) = o;
  }
}

// ---------------------------------------------------------------------------
// MFMA projection (R22): 32-row x 64-col tiles, grid (256,2) = 512 blocks.
// Waves: 16-row x 32-col strips. Fragment math HW-verified.
// ---------------------------------------------------------------------------
__launch_bounds__(256, 4)
__global__ void proj_kernel(const _Float16* __restrict__ Ah,
                            const float* __restrict__ W,
                            float* __restrict__ out) {
  __shared__ __align__(16) _Float16 Ahs[32][136];
  __shared__ __align__(16) _Float16 Whs[64][136];

  const int tid  = threadIdx.x;
  const int L    = tid & 63;
  const int wv   = tid >> 6;
  const int quad = L >> 4;
  const int ln   = L & 15;
  const int rowbase = blockIdx.x * 32;
  const int colbase = blockIdx.y * 64;

#pragma unroll
  for (int it = 0; it < 2; ++it) {
    const int idx = it * 256 + tid;     // 0..511 = 32 rows x 16 col-chunks
    const int r  = idx >> 4;
    const int c8 = idx & 15;
    *(uint4*)&Ahs[r][c8 * 8] =
        *(const uint4*)(Ah + (size_t)(rowbase + r) * EMB + c8 * 8);
  }
#pragma unroll
  for (int it = 0; it < 8; ++it) {
    const int idx = it * 256 + tid;
    const int n  = idx >> 5;
    const int c4 = idx & 31;
    const float4 w = *(const float4*)(W + (size_t)(colbase + n) * EMB + c4 * 4);
    v4h wh = {(_Float16)w.x, (_Float16)w.y, (_Float16)w.z, (_Float16)w.w};
    *(v4h*)&Whs[n][c4 * 4] = wh;
  }
  __syncthreads();

  const int rowoff = (wv & 1) * 16;
  const int coloff = (wv >> 1) * 32;

  v4f acc[2];
#pragma unroll
  for (int nt = 0; nt < 2; ++nt) acc[nt] = (v4f){0.f, 0.f, 0.f, 0.f};

#pragma unroll
  for (int k8 = 0; k8 < 8; ++k8) {
    const v4h af = *(const v4h*)&Ahs[rowoff + ln][k8 * 16 + quad * 4];
#pragma unroll
    for (int nt = 0; nt < 2; ++nt) {
      const v4h bf = *(const v4h*)&Whs[coloff + nt * 16 + ln][k8 * 16 + quad * 4];
      acc[nt] = __builtin_amdgcn_mfma_f32_16x16x16f16(af, bf, acc[nt], 0, 0, 0);
    }
  }

#pragma unroll
  for (int nt = 0; nt < 2; ++nt) {
    const int col = colbase + coloff + nt * 16 + ln;
#pragma unroll
    for (int r = 0; r < 4; ++r) {
      out[(size_t)(rowbase + rowoff + quad * 4 + r) * EMB + col] = acc[nt][r];
    }
  }
}

// ---------------------------------------------------------------------------
extern "C" void kernel_launch(void* const* d_in, const int* in_sizes, int n_in,
                              void* d_out, int out_size, void* d_ws, size_t ws_size,
                              hipStream_t stream) {
  const float* x     = (const float*)d_in[0];  // [4,2048,128]
  const float* theta = (const float*)d_in[1];  // [8]
  const float* w_out = (const float*)d_in[2];  // [128,128]
  float* out = (float*)d_out;                  // [4,2048,128]

  // workspace: Ah [8192][128] f16 (2 MB) | F1 [64][2048][8] f16 + 512-f16 pad
  // (kf prefetch overruns 1 tile at the last iter) | F2 [64][9][2048] f16
  _Float16* Ah = (_Float16*)d_ws;
  _Float16* F1 = Ah + (size_t)BATCH * SEQ * EMB;
  _Float16* F2 = F1 + (size_t)64 * SEQ * 8 + 512;

  // features once, both layouts: 64 bh x 8 s-chunks = 512 blocks
  feat_kernel<<<dim3(512), dim3(256), 0, stream>>>(x, theta, F1, F2);

  // dual-q attention, 8 waves/block (key quarters x q-pairs): 1024 blocks
  attn_kernel<<<dim3(1024), dim3(512), 0, stream>>>(F1, F2, Ah);

  // projection: 256 row-tiles x 2 col-tiles = 512 blocks
  proj_kernel<<<dim3((BATCH * SEQ) / 32, 2), dim3(256), 0, stream>>>(Ah, w_out, out);
}

// Round 9
// 95.500 us; speedup vs baseline: 3.4252x; 3.4252x over previous
//
#include <hip/hip_runtime.h>

#define BATCH 4
#define SEQ   2048
#define EMB   128
#define NH    16
#define DK    8

// log2(e) / sqrt(8): fold softmax temperature into exp2 (pre-multiplied into qf)
#define QSCALE 0.510069726f

typedef _Float16 v4h  __attribute__((ext_vector_type(4)));
typedef _Float16 v8h  __attribute__((ext_vector_type(8)));
typedef __fp16   v2fp __attribute__((ext_vector_type(2)));
typedef float    v4f  __attribute__((ext_vector_type(4)));
typedef float    v16f __attribute__((ext_vector_type(16)));

// ---------------------------------------------------------------------------
// R24 = R22 + vt 1-deep prefetch (single variable).
// Ledger: R23 spilled (launch_bounds 64-VGPR cap vs ~90 needed) -- occupancy
// lever permanently closed for this structure. R21 (asm, unscalarizable)
// proved exp issue ~free; per dual-iter slot = 679 cyc vs ~220 cyc of issue
// => ~400 cyc latency exposure. Prime suspect: vt0/vt1 are GLOBAL (L2,
// ~200-900 cyc) since R19, loaded and consumed in the SAME iteration with
// only the ~100-cyc exp block between (kf has a 1-deep prefetch; vt never
// did). This is also why R19 (LDS->global) regressed vs R18 despite
// removing all staging work. Fix: rotate vt through a 1-iter-ahead
// register pair (+16 VGPR, ~70 total, safe under the (256,4) cap of 128).
// Final iteration overreads 2 KB past F2 (workspace is huge; harmless).
//
// attn structure (R20/R22, HW-verified): each wave runs TWO q-chains (2
// q-tiles) against HALF the keys; kf/vt/addr/loop shared across chains;
// plain-exp partials additive, combined via 10 KB LDS.
// S^T = mfma_32x32x16(A=K, B=Q^T); C/D col=L&31, row=(reg&3)+8(reg>>2)+
// 4(L>>5). P=exp2(S^T) packs with pkrtz in natural order into the PV B-frag
// given the F2-baked key perm (bits 2<->3). qf=0 on half1 kills k=8..15
// padding. Ones-row 8 of F2 = denominator. |score*log2e/sqrt8| <= 4.1 so
// plain exp is exact (no max subtraction needed).
// ---------------------------------------------------------------------------

__launch_bounds__(256, 4)
__global__ void feat_kernel(const float* __restrict__ x,
                            const float* __restrict__ theta,
                            _Float16* __restrict__ F1,
                            _Float16* __restrict__ F2) {
  const int tid = threadIdx.x;
  const int bh  = blockIdx.x >> 3;          // 64 (b,h)
  const int s   = ((blockIdx.x & 7) << 8) + tid;
  const int b = bh >> 4, h = bh & 15;

  float th[8];
#pragma unroll
  for (int i = 0; i < 8; ++i) th[i] = theta[i];

  const float* xp = x + ((size_t)b * SEQ + s) * EMB + h * DK;
  const float4 a = *(const float4*)(xp);
  const float4 c = *(const float4*)(xp + 4);
  float r[8];
  r[0] = __cosf(a.x + th[0]);
  r[1] = r[0] * __cosf(a.y + th[1]);
  r[2] = r[1] * __cosf(a.z + th[2]);
  r[3] = r[2] * __cosf(a.w + th[3]);
  r[4] = r[3] * __cosf(c.x + th[4]);
  r[5] = r[4] * __cosf(c.y + th[5]);
  r[6] = r[5] * __cosf(c.z + th[6]);
  r[7] = r[6] * __cosf(c.w + th[7]);

  _Float16 hv[8];
#pragma unroll
  for (int i = 0; i < 8; ++i) hv[i] = (_Float16)r[i];

  // F1[bh][s][8]: 16 B contiguous store, s-consecutive lanes => coalesced
  union { v4h v[2]; float4 f; } u;
  u.v[0] = (v4h){hv[0], hv[1], hv[2], hv[3]};
  u.v[1] = (v4h){hv[4], hv[5], hv[6], hv[7]};
  *(float4*)(F1 + ((size_t)bh * SEQ + s) * 8) = u.f;

  // F2[bh][d][s_perm]: key-index bits 2<->3 swap baked in; per-d stores are
  // s-coalesced (permutation stays within each 16-group / 32 B)
  const int sp = (s & ~15) | (s & 3) | ((s & 4) << 1) | ((s & 8) >> 1);
  _Float16* f2 = F2 + (size_t)bh * 9 * SEQ;
#pragma unroll
  for (int d = 0; d < 8; ++d) f2[(size_t)d * SEQ + sp] = hv[d];
  f2[(size_t)8 * SEQ + s] = (_Float16)1.0f;   // denominator ones-row
}

__launch_bounds__(256, 4)
__global__ void attn_kernel(const _Float16* __restrict__ F1,
                            const _Float16* __restrict__ F2,
                            _Float16* __restrict__ Ah /* [B*S][128] f16 */) {
  __shared__ float P[4][2][5][64];          // 10 KB partial-combine buffer

  const int tid = threadIdx.x;
  const int L   = tid & 63;
  const int ln  = L & 31;
  const int hf  = L >> 5;                   // lane half
  const int wv  = tid >> 6;                 // wave 0..3
  const int pr  = wv >> 1;                  // q-pair 0..1
  const int kh  = wv & 1;                   // key half
  const int bh  = blockIdx.x >> 4;
  const int qbase = (blockIdx.x & 15) * 128;
  const int b = bh >> 4, h = bh & 15;
  const int mrow = (ln < 8) ? ln : 8;       // V^T row; ln>=8 -> ones-row 8

  const _Float16* f1 = F1 + (size_t)bh * SEQ * 8;
  const _Float16* kp = f1 + (size_t)(kh * 1024 + ln) * 8;   // this half's K rows
  const _Float16* vp = F2 + (size_t)bh * 9 * SEQ + (size_t)mrow * SEQ
                          + kh * 1024 + hf * 8;

  // two q-fragments (q-tiles 2*pr and 2*pr+1); half1 stays 0
  v8h qf0 = {0, 0, 0, 0, 0, 0, 0, 0};
  v8h qf1 = {0, 0, 0, 0, 0, 0, 0, 0};
  if (hf == 0) {
    const _Float16 qs = (_Float16)QSCALE;
    const v8h qsc = {qs, qs, qs, qs, qs, qs, qs, qs};
    qf0 = *(const v8h*)(f1 + (size_t)(qbase + pr * 64 + ln) * 8) * qsc;
    qf1 = *(const v8h*)(f1 + (size_t)(qbase + pr * 64 + 32 + ln) * 8) * qsc;
  }

  v16f acc0, acc1, zf;
#pragma unroll
  for (int i = 0; i < 16; ++i) { acc0[i] = 0.f; acc1[i] = 0.f; zf[i] = 0.f; }

  // ---- 32 K-tiles, dual chain; kf AND vt 1-deep register prefetch ----
  v8h kf = *(const v8h*)kp; kp += 256;
  v8h vt0_c = *(const v8h*)(vp);
  v8h vt1_c = *(const v8h*)(vp + 16); vp += 32;
#pragma unroll 4
  for (int kb = 0; kb < 32; ++kb) {
    // issue next-tile loads FIRST: a full ~680-cyc iteration now sits
    // between issue and consumption (L2 latency fully hidden)
    const v8h kf_n  = *(const v8h*)kp; kp += 256;
    const v8h vt0_n = *(const v8h*)(vp);
    const v8h vt1_n = *(const v8h*)(vp + 16); vp += 32;
    const v16f s0 = __builtin_amdgcn_mfma_f32_32x32x16_f16(kf, qf0, zf, 0, 0, 0);
    const v16f s1 = __builtin_amdgcn_mfma_f32_32x32x16_f16(kf, qf1, zf, 0, 0, 0);
    union { v2fp p[4]; v8h v; } a0, a1, b0, b1;
#pragma unroll
    for (int i = 0; i < 4; ++i) {
      a0.p[i] = __builtin_amdgcn_cvt_pkrtz(
          __builtin_amdgcn_exp2f(s0[2 * i]),
          __builtin_amdgcn_exp2f(s0[2 * i + 1]));
      a1.p[i] = __builtin_amdgcn_cvt_pkrtz(
          __builtin_amdgcn_exp2f(s0[8 + 2 * i]),
          __builtin_amdgcn_exp2f(s0[8 + 2 * i + 1]));
    }
    acc0 = __builtin_amdgcn_mfma_f32_32x32x16_f16(vt0_c, a0.v, acc0, 0, 0, 0);
    acc0 = __builtin_amdgcn_mfma_f32_32x32x16_f16(vt1_c, a1.v, acc0, 0, 0, 0);
#pragma unroll
    for (int i = 0; i < 4; ++i) {
      b0.p[i] = __builtin_amdgcn_cvt_pkrtz(
          __builtin_amdgcn_exp2f(s1[2 * i]),
          __builtin_amdgcn_exp2f(s1[2 * i + 1]));
      b1.p[i] = __builtin_amdgcn_cvt_pkrtz(
          __builtin_amdgcn_exp2f(s1[8 + 2 * i]),
          __builtin_amdgcn_exp2f(s1[8 + 2 * i + 1]));
    }
    acc1 = __builtin_amdgcn_mfma_f32_32x32x16_f16(vt0_c, b0.v, acc1, 0, 0, 0);
    acc1 = __builtin_amdgcn_mfma_f32_32x32x16_f16(vt1_c, b1.v, acc1, 0, 0, 0);
    kf = kf_n; vt0_c = vt0_n; vt1_c = vt1_n;
  }

  // ---- epilogue: combine key-half partials across the wave pair ----
  // acc C-layout: col=q=L&31, row=(reg&3)+8(reg>>2)+4*hf.
  // half0 regs 0-3 = dims 0-3, reg4 = row 8 = den; half1 regs 0-3 = dims 4-7.
#pragma unroll
  for (int r = 0; r < 5; ++r) {
    P[wv][0][r][L] = acc0[r];
    P[wv][1][r][L] = acc1[r];
  }
  __syncthreads();
  {
    const int p2 = (wv >> 1) << 1;      // pair base wave
    const int c  = wv & 1;              // this wave stores chain c => qtile wv
    float sum[4];
#pragma unroll
    for (int r = 0; r < 4; ++r) sum[r] = P[p2][c][r][L] + P[p2 + 1][c][r][L];
    const float den = P[p2][c][4][ln] + P[p2 + 1][c][4][ln];
    const float inv = 1.0f / den;
    const int qrow = qbase + wv * 32 + ln;
    v4h o = {(_Float16)(sum[0] * inv), (_Float16)(sum[1] * inv),
             (_Float16)(sum[2] * inv), (_Float16)(sum[3] * inv)};
    *(v4h*)(Ah + ((size_t)b * SEQ + qrow) * EMB + h * DK + hf * 4) = o;
  }
}

// ---------------------------------------------------------------------------
// MFMA projection (R22): 32-row x 64-col tiles, grid (256,2) = 512 blocks.
// Waves: 16-row x 32-col strips. Fragment math HW-verified.
// ---------------------------------------------------------------------------
__launch_bounds__(256, 4)
__global__ void proj_kernel(const _Float16* __restrict__ Ah,
                            const float* __restrict__ W,
                            float* __restrict__ out) {
  __shared__ __align__(16) _Float16 Ahs[32][136];
  __shared__ __align__(16) _Float16 Whs[64][136];

  const int tid  = threadIdx.x;
  const int L    = tid & 63;
  const int wv   = tid >> 6;
  const int quad = L >> 4;
  const int ln   = L & 15;
  const int rowbase = blockIdx.x * 32;
  const int colbase = blockIdx.y * 64;

#pragma unroll
  for (int it = 0; it < 2; ++it) {
    const int idx = it * 256 + tid;     // 0..511 = 32 rows x 16 col-chunks
    const int r  = idx >> 4;
    const int c8 = idx & 15;
    *(uint4*)&Ahs[r][c8 * 8] =
        *(const uint4*)(Ah + (size_t)(rowbase + r) * EMB + c8 * 8);
  }
#pragma unroll
  for (int it = 0; it < 8; ++it) {
    const int idx = it * 256 + tid;
    const int n  = idx >> 5;
    const int c4 = idx & 31;
    const float4 w = *(const float4*)(W + (size_t)(colbase + n) * EMB + c4 * 4);
    v4h wh = {(_Float16)w.x, (_Float16)w.y, (_Float16)w.z, (_Float16)w.w};
    *(v4h*)&Whs[n][c4 * 4] = wh;
  }
  __syncthreads();

  const int rowoff = (wv & 1) * 16;
  const int coloff = (wv >> 1) * 32;

  v4f acc[2];
#pragma unroll
  for (int nt = 0; nt < 2; ++nt) acc[nt] = (v4f){0.f, 0.f, 0.f, 0.f};

#pragma unroll
  for (int k8 = 0; k8 < 8; ++k8) {
    const v4h af = *(const v4h*)&Ahs[rowoff + ln][k8 * 16 + quad * 4];
#pragma unroll
    for (int nt = 0; nt < 2; ++nt) {
      const v4h bf = *(const v4h*)&Whs[coloff + nt * 16 + ln][k8 * 16 + quad * 4];
      acc[nt] = __builtin_amdgcn_mfma_f32_16x16x16f16(af, bf, acc[nt], 0, 0, 0);
    }
  }

#pragma unroll
  for (int nt = 0; nt < 2; ++nt) {
    const int col = colbase + coloff + nt * 16 + ln;
#pragma unroll
    for (int r = 0; r < 4; ++r) {
      out[(size_t)(rowbase + rowoff + quad * 4 + r) * EMB + col] = acc[nt][r];
    }
  }
}

// ---------------------------------------------------------------------------
extern "C" void kernel_launch(void* const* d_in, const int* in_sizes, int n_in,
                              void* d_out, int out_size, void* d_ws, size_t ws_size,
                              hipStream_t stream) {
  const float* x     = (const float*)d_in[0];  // [4,2048,128]
  const float* theta = (const float*)d_in[1];  // [8]
  const float* w_out = (const float*)d_in[2];  // [128,128]
  float* out = (float*)d_out;                  // [4,2048,128]

  // workspace: Ah [8192][128] f16 (2 MB) | F1 [64][2048][8] f16 + 512-f16 pad
  // (kf prefetch overruns 1 tile at the last iter) | F2 [64][9][2048] f16
  // (+2 KB tail overread by the vt prefetch; workspace is far larger)
  _Float16* Ah = (_Float16*)d_ws;
  _Float16* F1 = Ah + (size_t)BATCH * SEQ * EMB;
  _Float16* F2 = F1 + (size_t)64 * SEQ * 8 + 512;

  // features once, both layouts: 64 bh x 8 s-chunks = 512 blocks
  feat_kernel<<<dim3(512), dim3(256), 0, stream>>>(x, theta, F1, F2);

  // dual-q attention: 64 bh x 16 q-blocks = 1024 blocks, 4 waves
  attn_kernel<<<dim3(1024), dim3(256), 0, stream>>>(F1, F2, Ah);

  // projection: 256 row-tiles x 2 col-tiles = 512 blocks
  proj_kernel<<<dim3((BATCH * SEQ) / 32, 2), dim3(256), 0, stream>>>(Ah, w_out, out);
}

// Round 11
// 93.724 us; speedup vs baseline: 3.4901x; 1.0189x over previous
//
#include <hip/hip_runtime.h>

#define BATCH 4
#define SEQ   2048
#define EMB   128
#define NH    16
#define DK    8

// log2(e) / sqrt(8): fold softmax temperature into exp2 (pre-multiplied into qf)
#define QSCALE 0.510069726f

typedef _Float16 v4h  __attribute__((ext_vector_type(4)));
typedef _Float16 v8h  __attribute__((ext_vector_type(8)));
typedef __fp16   v2fp __attribute__((ext_vector_type(2)));
typedef float    v4f  __attribute__((ext_vector_type(4)));
typedef float    v16f __attribute__((ext_vector_type(16)));

#define CHUNK  512
#define NCH    (SEQ / CHUNK)   // 4
#define VTP    520             // VT col pitch (f16): 260 dwords %32 = 4 -> 2-way max

// ---------------------------------------------------------------------------
// R26: in-LDS feat staging (R15/R18) + dual-q inner loop (R20) -- the
// combination never tried. R25's cooperative fusion failed (launch error in
// graph capture => output never written); grid.sync is unavailable. But the
// feat->attn fusion needs NO grid barrier: R19 proved global-F staging is
// neutral for attn duration while COSTING a 4.5us feat kernel + launch gap.
// Here: 512 blocks x 256 thr; block owns 256 q rows (qg=bid&7) of one (b,h);
// each wave owns TWO q-tiles (64 rows) and iterates ALL keys in 4 staged
// 512-key chunks (R15 staging verbatim); inner loop = R20 dual-chain with
// LDS kf/vt. No F workspace, no feat kernel. Epilogue = R15 shfl-den
// normalize per chain (no cross-wave combine: each wave sees all keys).
// Occupancy: 2 blocks/CU (8 waves/CU); prior 4<->8 waves/SIMD tests were
// flat -- 2/SIMD is the one new variable to watch.
//
// Layouts (HW-verified): S^T = mfma_32x32x16(A=K, B=Q^T); C/D col=L&31,
// row=(reg&3)+8(reg>>2)+4(L>>5). P=exp2(S^T) packs with pkrtz in natural reg
// order into the PV B-frag PROVIDED V^T is stored with key-index bits 2<->3
// swapped (VT staging perm). qf=0 on half1 kills k=8..15 padding. Ones-row
// d=8 of V^T = softmax denominator; rows 9..31 garbage never stored.
// |score*log2e/sqrt8| <= 4.1 so plain exp is exact.
// ---------------------------------------------------------------------------
__launch_bounds__(256, 4)
__global__ void attn_kernel(const float* __restrict__ x,
                            const float* __restrict__ theta,
                            _Float16* __restrict__ Ah /* [B*S][128] f16 */) {
  __shared__ __align__(16) _Float16 Kl[CHUNK * 8];   // 8 KB: [key][8 dims]
  __shared__ __align__(16) _Float16 VT[10][VTP];     // 10.2 KB: d 0-7, 8=ones, 9=junk

  const int tid = threadIdx.x;
  const int L   = tid & 63;
  const int ln  = L & 31;
  const int hf  = L >> 5;           // lane half
  const int wv  = tid >> 6;         // wave 0..3
  const int bh  = blockIdx.x >> 3;  // 64 (b,h)
  const int qg  = blockIdx.x & 7;   // 256-row q group
  const int b = bh >> 4;
  const int h = bh & 15;

  float th[DK];
#pragma unroll
  for (int i = 0; i < DK; ++i) th[i] = theta[i];

  // VT row 8 = ones (denominator; persists across restages), row 9 = 0
  for (int i = tid; i < VTP; i += 256) {
    VT[8][i] = (_Float16)1.0f;
    VT[9][i] = (_Float16)0.0f;
  }

  const int c0 = qg >> 1;           // 512-chunk containing this block's q rows
  const int mrow = (ln < 9) ? ln : 9;   // clamped VT row for PV A-frag
  const float* xb = x + (size_t)b * SEQ * EMB + h * DK;

  float4 pa0, pa1, pb0, pb1;        // prefetched x rows (keys tid, tid+256)
  {
    const float* xp = xb + (size_t)(c0 * CHUNK + tid) * EMB;
    pa0 = *(const float4*)(xp);
    pa1 = *(const float4*)(xp + 4);
    pb0 = *(const float4*)(xp + 256 * EMB);
    pb1 = *(const float4*)(xp + 256 * EMB + 4);
  }

  v8h qf0 = {0, 0, 0, 0, 0, 0, 0, 0};
  v8h qf1 = {0, 0, 0, 0, 0, 0, 0, 0};
  v16f acc0, acc1, zf;
#pragma unroll
  for (int i = 0; i < 16; ++i) { acc0[i] = 0.f; acc1[i] = 0.f; zf[i] = 0.f; }

  for (int cc = 0; cc < NCH; ++cc) {
    if (cc) __syncthreads();

    // ---- stage: features for keys tid, tid+256 (16 B/lane Kl writes) ----
    {
      float r0[8], r1[8];
      r0[0] = __cosf(pa0.x + th[0]);
      r0[1] = r0[0] * __cosf(pa0.y + th[1]);
      r0[2] = r0[1] * __cosf(pa0.z + th[2]);
      r0[3] = r0[2] * __cosf(pa0.w + th[3]);
      r0[4] = r0[3] * __cosf(pa1.x + th[4]);
      r0[5] = r0[4] * __cosf(pa1.y + th[5]);
      r0[6] = r0[5] * __cosf(pa1.z + th[6]);
      r0[7] = r0[6] * __cosf(pa1.w + th[7]);
      r1[0] = __cosf(pb0.x + th[0]);
      r1[1] = r1[0] * __cosf(pb0.y + th[1]);
      r1[2] = r1[1] * __cosf(pb0.z + th[2]);
      r1[3] = r1[2] * __cosf(pb0.w + th[3]);
      r1[4] = r1[3] * __cosf(pb1.x + th[4]);
      r1[5] = r1[4] * __cosf(pb1.y + th[5]);
      r1[6] = r1[5] * __cosf(pb1.z + th[6]);
      r1[7] = r1[6] * __cosf(pb1.w + th[7]);

      _Float16 h0[8], h1[8];
#pragma unroll
      for (int i = 0; i < 8; ++i) { h0[i] = (_Float16)r0[i]; h1[i] = (_Float16)r1[i]; }

      union { v4h v[2]; float4 f; } u0, u1;
      u0.v[0] = (v4h){h0[0], h0[1], h0[2], h0[3]};
      u0.v[1] = (v4h){h0[4], h0[5], h0[6], h0[7]};
      u1.v[0] = (v4h){h1[0], h1[1], h1[2], h1[3]};
      u1.v[1] = (v4h){h1[4], h1[5], h1[6], h1[7]};
      *(float4*)&Kl[tid * 8]         = u0.f;
      *(float4*)&Kl[(tid + 256) * 8] = u1.f;

      // VT with within-16 slot perm (swap bits 2<->3 of key index)
      const int j0 = tid, j1 = tid + 256;
      const int col0 = (j0 & ~15) | (j0 & 3) | ((j0 & 4) << 1) | ((j0 & 8) >> 1);
      const int col1 = (j1 & ~15) | (j1 & 3) | ((j1 & 4) << 1) | ((j1 & 8) >> 1);
#pragma unroll
      for (int d = 0; d < 8; ++d) {
        VT[d][col0] = h0[d];
        VT[d][col1] = h1[d];
      }
    }
    __syncthreads();

    // prefetch next chunk's x rows (consumed after the compute phase)
    if (cc + 1 < NCH) {
      const int cn = (c0 + cc + 1) & (NCH - 1);
      const float* xp = xb + (size_t)(cn * CHUNK + tid) * EMB;
      pa0 = *(const float4*)(xp);
      pa1 = *(const float4*)(xp + 4);
      pb0 = *(const float4*)(xp + 256 * EMB);
      pb1 = *(const float4*)(xp + 256 * EMB + 4);
    }

    // qf for BOTH chains from Kl on the q-containing chunk (visited first)
    if (cc == 0 && hf == 0) {
      const int ql = (qg & 1) * 256 + wv * 64 + ln;   // local row in chunk c0
      const _Float16 qs = (_Float16)QSCALE;
      const v8h qsc = {qs, qs, qs, qs, qs, qs, qs, qs};
      qf0 = *(const v8h*)&Kl[ql * 8] * qsc;
      qf1 = *(const v8h*)&Kl[(ql + 32) * 8] * qsc;
    }

    // ---- compute: 16 32-key tiles, dual chain, kf 1-deep LDS prefetch ----
    v8h kf = *(const v8h*)&Kl[ln * 8];
#pragma unroll 2
    for (int kb = 0; kb < CHUNK / 32; ++kb) {
      const v8h kf_n = *(const v8h*)&Kl[((((kb + 1) & 15) * 32) + ln) * 8];
      const v16f s0 = __builtin_amdgcn_mfma_f32_32x32x16_f16(kf, qf0, zf, 0, 0, 0);
      const v16f s1 = __builtin_amdgcn_mfma_f32_32x32x16_f16(kf, qf1, zf, 0, 0, 0);
      const v8h vt0 = *(const v8h*)&VT[mrow][kb * 32 + hf * 8];
      const v8h vt1 = *(const v8h*)&VT[mrow][kb * 32 + 16 + hf * 8];
      union { v2fp p[4]; v8h v; } a0, a1, b0, b1;
#pragma unroll
      for (int i = 0; i < 4; ++i) {
        a0.p[i] = __builtin_amdgcn_cvt_pkrtz(
            __builtin_amdgcn_exp2f(s0[2 * i]),
            __builtin_amdgcn_exp2f(s0[2 * i + 1]));
        a1.p[i] = __builtin_amdgcn_cvt_pkrtz(
            __builtin_amdgcn_exp2f(s0[8 + 2 * i]),
            __builtin_amdgcn_exp2f(s0[8 + 2 * i + 1]));
      }
      acc0 = __builtin_amdgcn_mfma_f32_32x32x16_f16(vt0, a0.v, acc0, 0, 0, 0);
      acc0 = __builtin_amdgcn_mfma_f32_32x32x16_f16(vt1, a1.v, acc0, 0, 0, 0);
#pragma unroll
      for (int i = 0; i < 4; ++i) {
        b0.p[i] = __builtin_amdgcn_cvt_pkrtz(
            __builtin_amdgcn_exp2f(s1[2 * i]),
            __builtin_amdgcn_exp2f(s1[2 * i + 1]));
        b1.p[i] = __builtin_amdgcn_cvt_pkrtz(
            __builtin_amdgcn_exp2f(s1[8 + 2 * i]),
            __builtin_amdgcn_exp2f(s1[8 + 2 * i + 1]));
      }
      acc1 = __builtin_amdgcn_mfma_f32_32x32x16_f16(vt0, b0.v, acc1, 0, 0, 0);
      acc1 = __builtin_amdgcn_mfma_f32_32x32x16_f16(vt1, b1.v, acc1, 0, 0, 0);
      kf = kf_n;
    }
  }

  // ---- epilogue: normalize both chains (each wave saw ALL keys) ----
  // acc C-layout: col=q=L&31, row=(reg&3)+8(reg>>2)+4*hf.
  // half0 regs 0-3 = dims 0-3, reg4 = row 8 = den; half1 regs 0-3 = dims 4-7.
  {
    const int qrow0 = qg * 256 + wv * 64 + ln;
    const float den0 = __shfl(acc0[4], ln, 64);   // from half0 lane ln
    const float inv0 = 1.0f / den0;
    v4h o0 = {(_Float16)(acc0[0] * inv0), (_Float16)(acc0[1] * inv0),
              (_Float16)(acc0[2] * inv0), (_Float16)(acc0[3] * inv0)};
    *(v4h*)(Ah + ((size_t)b * SEQ + qrow0) * EMB + h * DK + hf * 4) = o0;

    const float den1 = __shfl(acc1[4], ln, 64);
    const float inv1 = 1.0f / den1;
    v4h o1 = {(_Float16)(acc1[0] * inv1), (_Float16)(acc1[1] * inv1),
              (_Float16)(acc1[2] * inv1), (_Float16)(acc1[3] * inv1)};
    *(v4h*)(Ah + ((size_t)b * SEQ + qrow0 + 32) * EMB + h * DK + hf * 4) = o1;
  }
}

// ---------------------------------------------------------------------------
// MFMA projection (R22): 32-row x 64-col tiles, grid (256,2) = 512 blocks.
// Waves: 16-row x 32-col strips. Fragment math HW-verified.
// ---------------------------------------------------------------------------
__launch_bounds__(256, 4)
__global__ void proj_kernel(const _Float16* __restrict__ Ah,
                            const float* __restrict__ W,
                            float* __restrict__ out) {
  __shared__ __align__(16) _Float16 Ahs[32][136];
  __shared__ __align__(16) _Float16 Whs[64][136];

  const int tid  = threadIdx.x;
  const int L    = tid & 63;
  const int wv   = tid >> 6;
  const int quad = L >> 4;
  const int ln   = L & 15;
  const int rowbase = blockIdx.x * 32;
  const int colbase = blockIdx.y * 64;

#pragma unroll
  for (int it = 0; it < 2; ++it) {
    const int idx = it * 256 + tid;     // 0..511 = 32 rows x 16 col-chunks
    const int r  = idx >> 4;
    const int c8 = idx & 15;
    *(uint4*)&Ahs[r][c8 * 8] =
        *(const uint4*)(Ah + (size_t)(rowbase + r) * EMB + c8 * 8);
  }
#pragma unroll
  for (int it = 0; it < 8; ++it) {
    const int idx = it * 256 + tid;
    const int n  = idx >> 5;
    const int c4 = idx & 31;
    const float4 w = *(const float4*)(W + (size_t)(colbase + n) * EMB + c4 * 4);
    v4h wh = {(_Float16)w.x, (_Float16)w.y, (_Float16)w.z, (_Float16)w.w};
    *(v4h*)&Whs[n][c4 * 4] = wh;
  }
  __syncthreads();

  const int rowoff = (wv & 1) * 16;
  const int coloff = (wv >> 1) * 32;

  v4f acc[2];
#pragma unroll
  for (int nt = 0; nt < 2; ++nt) acc[nt] = (v4f){0.f, 0.f, 0.f, 0.f};

#pragma unroll
  for (int k8 = 0; k8 < 8; ++k8) {
    const v4h af = *(const v4h*)&Ahs[rowoff + ln][k8 * 16 + quad * 4];
#pragma unroll
    for (int nt = 0; nt < 2; ++nt) {
      const v4h bf = *(const v4h*)&Whs[coloff + nt * 16 + ln][k8 * 16 + quad * 4];
      acc[nt] = __builtin_amdgcn_mfma_f32_16x16x16f16(af, bf, acc[nt], 0, 0, 0);
    }
  }

#pragma unroll
  for (int nt = 0; nt < 2; ++nt) {
    const int col = colbase + coloff + nt * 16 + ln;
#pragma unroll
    for (int r = 0; r < 4; ++r) {
      out[(size_t)(rowbase + rowoff + quad * 4 + r) * EMB + col] = acc[nt][r];
    }
  }
}

// ---------------------------------------------------------------------------
extern "C" void kernel_launch(void* const* d_in, const int* in_sizes, int n_in,
                              void* d_out, int out_size, void* d_ws, size_t ws_size,
                              hipStream_t stream) {
  const float* x     = (const float*)d_in[0];  // [4,2048,128]
  const float* theta = (const float*)d_in[1];  // [8]
  const float* w_out = (const float*)d_in[2];  // [128,128]
  float* out = (float*)d_out;                  // [4,2048,128]

  _Float16* Ah = (_Float16*)d_ws;              // [8192][128] f16 = 2 MB

  // fused features + dual-q attention: 64 bh x 8 q-groups = 512 blocks
  attn_kernel<<<dim3(512), dim3(256), 0, stream>>>(x, theta, Ah);

  // projection: 256 row-tiles x 2 col-tiles = 512 blocks
  proj_kernel<<<dim3((BATCH * SEQ) / 32, 2), dim3(256), 0, stream>>>(Ah, w_out, out);
}